// Round 4
// baseline (426.006 us; speedup 1.0000x reference)
//
#include <hip/hip_runtime.h>
#include <math.h>

// Problem: B=4, S=4096, D=2048, E=64, TOP_K=2
#define M_TOK 16384
#define D_DIM 2048
#define E_EXP 64
#define NCOL  128              // route cols 0..63 | noise cols 64..127
#define BM    32               // tokens per block (2 blocks/CU)
#define BK    64               // K per main-loop iteration (2 MFMA substeps of 32)
#define NITER (D_DIM / BK)     // 32

// LDS: A limbs, frag-linear. Per row: 128B payload (64 k bf16) + 16B skew.
// Row stride 144B = 36 words; 36 % 32 = 4 -> bank quad = 4*((row+chunk)&7),
// 8 lanes/quad for full-wave b128 reads (balanced, no XOR).
#define ROW_STRIDE 144
#define PLANE (BM * ROW_STRIDE)        // 4608 B per limb plane
#define BUFSZ (3 * PLANE)              // 13824 B per K-tile buffer (3 limbs)
#define SMEM_BYTES (2 * BUFSZ)         // 27648 B (epilogue Llds aliases: 32*132*4=16.9KB)

typedef float         f32x4  __attribute__((ext_vector_type(4)));
typedef short         bf16x8 __attribute__((ext_vector_type(8)));
typedef unsigned int  uint;

#define MFMA_B16(a, b, c) __builtin_amdgcn_mfma_f32_16x16x32_bf16((a), (b), (c), 0, 0, 0)

// f32 -> bf16 round-to-nearest-even (used for limb 2 and for prep_w)
__device__ __forceinline__ unsigned short bfrne(float f) {
    unsigned int u = __float_as_uint(f);
    return (unsigned short)((u + 0x7fffu + ((u >> 16) & 1u)) >> 16);
}
__device__ __forceinline__ float bfhi(unsigned short h) {
    return __uint_as_float((unsigned int)h << 16);
}

// jax.lax.top_k order: larger value first; ties -> lower index first
__device__ __forceinline__ bool beats(float va, int ia, float vb, int ib) {
    return (va > vb) || (va == vb && ia < ib);
}

// ---------------- prep: split W_route|W_noise into 3 bf16 limbs, frag-linear ----------
// Wg layout (16B units): [kblk 0..63][limb 0..2][cf 0..7][lane 0..63]
//   cf 0..3 -> route cols cf*16+(lane&15); cf 4..7 -> noise cols (cf-4)*16+(lane&15)
//   lane holds k = kblk*32 + (lane>>4)*8 + j  (exactly the mfma_16x16x32 B-frag order)
__global__ __launch_bounds__(256) void prep_w(
    const float* __restrict__ Wr, const float* __restrict__ Wn,
    unsigned short* __restrict__ Wg)
{
    const int g    = blockIdx.x * 256 + threadIdx.x;   // 0..32767
    const int lane = g & 63;
    const int cf   = (g >> 6) & 7;
    const int kblk = g >> 9;                           // 0..63
    const int colL = (cf & 3) * 16 + (lane & 15);
    const float* __restrict__ W = (cf < 4) ? Wr : Wn;
    const int kbase = kblk * 32 + (lane >> 4) * 8;

    bf16x8 o0, o1, o2;
    #pragma unroll
    for (int j = 0; j < 8; ++j) {
        const float w = W[(size_t)(kbase + j) * E_EXP + colL];
        const unsigned short h0 = bfrne(w);
        const float r  = w - bfhi(h0);              // exact
        const unsigned short h1 = bfrne(r);
        const float r2 = r - bfhi(h1);              // exact
        const unsigned short h2 = bfrne(r2);
        o0[j] = (short)h0; o1[j] = (short)h1; o2[j] = (short)h2;
    }
    const size_t s0 = (((size_t)kblk * 3 + 0) * 8 + cf) * 64 + lane;
    const size_t s1 = (((size_t)kblk * 3 + 1) * 8 + cf) * 64 + lane;
    const size_t s2 = (((size_t)kblk * 3 + 2) * 8 + cf) * 64 + lane;
    *(bf16x8*)(Wg + s0 * 8) = o0;
    *(bf16x8*)(Wg + s1 * 8) = o1;
    *(bf16x8*)(Wg + s2 * 8) = o2;
}

// ---------------- fused: 3-limb bf16 MFMA GEMM + softplus + top-2 + softmax ----------
__device__ __forceinline__ void load_b(const unsigned short* __restrict__ Wg,
                                       int it, int wc, int lane,
                                       bf16x8 (&Bv)[2][2][3])
{
    #pragma unroll
    for (int s = 0; s < 2; ++s) {
        const int kblk = it * 2 + s;
        #pragma unroll
        for (int cfi = 0; cfi < 2; ++cfi) {
            #pragma unroll
            for (int p = 0; p < 3; ++p) {
                const size_t idx = (((size_t)kblk * 3 + p) * 8 + (wc * 2 + cfi)) * 64 + lane;
                Bv[s][cfi][p] = *(const bf16x8*)(Wg + idx * 8);
            }
        }
    }
}

// A tile 32 tok x 64 k: one float4 per thread (512 threads * 16B = 8KB)
__device__ __forceinline__ void load_a(const float* __restrict__ A, int tokBase,
                                       int it, int tid, float4& x)
{
    const int row = tid >> 4;          // 0..31
    const int kc  = tid & 15;          // 4-float chunk within the 64-wide K tile
    x = *(const float4*)(A + (size_t)(tokBase + row) * D_DIM + it * BK + kc * 4);
}

// split this thread's 4 A-floats into 3 bf16 limb half-chunks; store b64 to LDS
// limbs 0,1 by truncation (hi bits already positioned -> cheap pack);
// limb 2 by RNE. Residuals exact; total split residual <= 2^-25 relative.
__device__ __forceinline__ void cvt_store(char* smem, int buf, int tid, const float4& x)
{
    const float v[4] = {x.x, x.y, x.z, x.w};
    uint t0[4], t1[4]; unsigned short h2[4];
    #pragma unroll
    for (int j = 0; j < 4; ++j) {
        const uint u = __float_as_uint(v[j]);
        t0[j] = u & 0xffff0000u;
        const float r = v[j] - __uint_as_float(t0[j]);      // exact
        const uint ru = __float_as_uint(r);
        t1[j] = ru & 0xffff0000u;
        const float r2 = r - __uint_as_float(t1[j]);        // exact
        h2[j] = bfrne(r2);
    }
    uint2 w0, w1, w2;
    w0.x = (t0[0] >> 16) | t0[1];  w0.y = (t0[2] >> 16) | t0[3];
    w1.x = (t1[0] >> 16) | t1[1];  w1.y = (t1[2] >> 16) | t1[3];
    w2.x = (uint)h2[0] | ((uint)h2[1] << 16);
    w2.y = (uint)h2[2] | ((uint)h2[3] << 16);

    const int row = tid >> 4;
    const int kc  = tid & 15;          // 8B chunk within the 128B row
    char* base = smem + buf * BUFSZ + row * ROW_STRIDE + kc * 8;
    *(uint2*)(base)             = w0;
    *(uint2*)(base + PLANE)     = w1;
    *(uint2*)(base + 2 * PLANE) = w2;
}

__device__ __forceinline__ void compute_iter(const char* Ab, int wr, int lane,
                                             const bf16x8 (&Bc)[2][2][3],
                                             f32x4 (&acch)[2], f32x4 (&accl)[2])
{
    #pragma unroll
    for (int s = 0; s < 2; ++s) {
        const int row = wr * 16 + (lane & 15);
        const int off = row * ROW_STRIDE + (s * 4 + (lane >> 4)) * 16;
        const bf16x8 a0 = *(const bf16x8*)(Ab + off);
        const bf16x8 a1 = *(const bf16x8*)(Ab + PLANE + off);
        const bf16x8 a2 = *(const bf16x8*)(Ab + 2 * PLANE + off);
        #pragma unroll
        for (int cfi = 0; cfi < 2; ++cfi) {
            // hi limb product -> short dep chain in acch; 5 low products -> accl
            acch[cfi] = MFMA_B16(a0, Bc[s][cfi][0], acch[cfi]);
            accl[cfi] = MFMA_B16(a0, Bc[s][cfi][1], accl[cfi]);
            accl[cfi] = MFMA_B16(a1, Bc[s][cfi][0], accl[cfi]);
            accl[cfi] = MFMA_B16(a1, Bc[s][cfi][1], accl[cfi]);
            accl[cfi] = MFMA_B16(a0, Bc[s][cfi][2], accl[cfi]);
            accl[cfi] = MFMA_B16(a2, Bc[s][cfi][0], accl[cfi]);
        }
    }
}

#define LL_LD 132   // Llds row stride (floats): 16B-aligned rows, 132%32=4 skew

__global__ __launch_bounds__(512, 4) void fused_router(
    const float* __restrict__ A,
    const unsigned short* __restrict__ Wg,
    const float* __restrict__ br, const float* __restrict__ bn,
    const float* __restrict__ noise,
    float* __restrict__ probs, float* __restrict__ idxo)
{
    __shared__ __align__(16) char smem[SMEM_BYTES];   // A limbs (2 buf); epilogue aliases

    const int tid  = threadIdx.x;
    const int lane = tid & 63;
    const int wid  = tid >> 6;       // 0..7
    const int wr   = wid >> 2;       // token half  (16 tokens)
    const int wc   = wid & 3;        // col quarter (32 of 128 cols)
    const int tokBase = blockIdx.x * BM;

    f32x4 acch[2], accl[2];
    const f32x4 zero4 = {0.f, 0.f, 0.f, 0.f};
    acch[0] = zero4; acch[1] = zero4; accl[0] = zero4; accl[1] = zero4;

    bf16x8 B0[2][2][3], B1[2][2][3];
    float4 xE, xO;

    // prologue: limbs(0) -> buf0; A(1) in flight; B(0) in regs
    load_a(A, tokBase, 0, tid, xE);
    load_b(Wg, 0, wc, lane, B0);
    load_a(A, tokBase, 1, tid, xO);
    cvt_store(smem, 0, tid, xE);
    __syncthreads();

    #pragma unroll 1
    for (int it2 = 0; it2 < NITER / 2; ++it2) {
        const int ita = it2 * 2;
        const int itb = ita + 1;              // < NITER (NITER even)

        load_b(Wg, itb, wc, lane, B1);        // B for the odd sub-iter
        cvt_store(smem, 1, tid, xO);          // limbs(itb) -> buf1
        if (ita + 2 < NITER) load_a(A, tokBase, ita + 2, tid, xE);   // deep prefetch
        compute_iter(smem, wr, lane, B0, acch, accl);                // consume buf0
        __syncthreads();                      // buf1 ready; buf0 reads done

        if (itb + 1 < NITER) load_b(Wg, itb + 1, wc, lane, B0);
        if (ita + 2 < NITER) cvt_store(smem, 0, tid, xE);            // limbs(ita+2) -> buf0
        if (itb + 2 < NITER) load_a(A, tokBase, itb + 2, tid, xO);
        compute_iter(smem + BUFSZ, wr, lane, B1, acch, accl);        // consume buf1
        __syncthreads();                      // buf0 ready; buf1 reads done
    }

    // ---- accumulators -> LDS logits (C layout: col=lane&15, row=(lane>>4)*4+reg) ----
    float (*Llds)[LL_LD] = (float (*)[LL_LD])smem;   // 32 x 132 f32, aliases A bufs
    #pragma unroll
    for (int cfi = 0; cfi < 2; ++cfi) {
        const int col  = wc * 32 + cfi * 16 + (lane & 15);
        const int rowb = wr * 16 + (lane >> 4) * 4;
        #pragma unroll
        for (int r = 0; r < 4; ++r)
            Llds[rowb + r][col] = acch[cfi][r] + accl[cfi][r];
    }
    __syncthreads();

    // ---- fused epilogue: 16 lanes per token, 4 experts each (f32) ----
    const int token = tid >> 4;          // 0..31
    const int s16   = tid & 15;
    const int tokG  = tokBase + token;

    float v0 = -INFINITY, v1 = -INFINITY;
    int i0 = 0, i1 = 0;
    {
        const float4 n4 = *(const float4*)(noise + (size_t)tokG * E_EXP + s16 * 4);
        const float4 b4 = *(const float4*)(br + s16 * 4);
        const float4 c4 = *(const float4*)(bn + s16 * 4);
        const float4 l4 = *(const float4*)(&Llds[token][s16 * 4]);
        const float4 m4 = *(const float4*)(&Llds[token][64 + s16 * 4]);
        const float nv[4] = {n4.x, n4.y, n4.z, n4.w};
        const float bv[4] = {b4.x, b4.y, b4.z, b4.w};
        const float cv[4] = {c4.x, c4.y, c4.z, c4.w};
        const float lv[4] = {l4.x, l4.y, l4.z, l4.w};
        const float mv[4] = {m4.x, m4.y, m4.z, m4.w};
        #pragma unroll
        for (int j = 0; j < 4; ++j) {
            const int e = s16 * 4 + j;
            const float lg = lv[j] + bv[j];
            const float nl = mv[j] + cv[j];
            const float sp = fmaxf(nl, 0.0f) + log1pf(expf(-fabsf(nl)));   // softplus
            const float v  = fmaf(nv[j], sp, lg);
            if (beats(v, e, v0, i0))      { v1 = v0; i1 = i0; v0 = v; i0 = e; }
            else if (beats(v, e, v1, i1)) { v1 = v;  i1 = e; }
        }
    }
    // merge across the token's 16 lanes (aligned group, masks 1,2,4,8)
    #pragma unroll
    for (int m = 1; m < 16; m <<= 1) {
        const float w0 = __shfl_xor(v0, m), w1 = __shfl_xor(v1, m);
        const int   j0 = __shfl_xor(i0, m), j1 = __shfl_xor(i1, m);
        if (beats(v0, i0, w0, j0)) {
            if (!beats(v1, i1, w0, j0)) { v1 = w0; i1 = j0; }
        } else {
            if (beats(v0, i0, w1, j1)) { v1 = v0; i1 = i0; }
            else                       { v1 = w1; i1 = j1; }
            v0 = w0; i0 = j0;
        }
    }
    const float e1  = expf(v1 - v0);     // <= 1
    const float den = 1.0f + e1;
    const float p0 = 1.0f / den;
    const float p1 = e1 / den;

    // every lane writes its own 4 cols -> no cross-thread write ordering needed
    float out[4];
    #pragma unroll
    for (int j = 0; j < 4; ++j) {
        const int e = s16 * 4 + j;
        out[j] = (e == i0) ? p0 : ((e == i1) ? p1 : 0.0f);
    }
    *(float4*)(probs + (size_t)tokG * E_EXP + s16 * 4) =
        make_float4(out[0], out[1], out[2], out[3]);
    if (s16 == 0)
        *(float2*)(idxo + (size_t)tokG * 2) = make_float2((float)i0, (float)i1);
}

extern "C" void kernel_launch(void* const* d_in, const int* in_sizes, int n_in,
                              void* d_out, int out_size, void* d_ws, size_t ws_size,
                              hipStream_t stream) {
    (void)in_sizes; (void)n_in; (void)out_size; (void)ws_size;
    const float* A  = (const float*)d_in[0];   // mh_output [4,4096,2048]
    const float* Wr = (const float*)d_in[1];   // W_route   [2048,64]
    const float* br = (const float*)d_in[2];   // b_route   [64]
    const float* Wn = (const float*)d_in[3];   // W_noise   [2048,64]
    const float* bn = (const float*)d_in[4];   // b_noise   [64]
    const float* nz = (const float*)d_in[5];   // noise     [4,4096,64]

    float* probs = (float*)d_out;                    // [4,4096,64] f32
    float* idxo  = probs + (size_t)M_TOK * E_EXP;    // [4,4096,2] as float

    unsigned short* Wg = (unsigned short*)d_ws;      // 1.5 MB split-W, frag-linear

    prep_w<<<128, 256, 0, stream>>>(Wr, Wn, Wg);
    fused_router<<<M_TOK / BM, 512, 0, stream>>>(A, Wg, br, bn, nz, probs, idxo);
}

// Round 5
// 240.932 us; speedup vs baseline: 1.7682x; 1.7682x over previous
//
#include <hip/hip_runtime.h>
#include <math.h>

// Problem: B=4, S=4096, D=2048, E=64, TOP_K=2
#define M_TOK 16384
#define D_DIM 2048
#define E_EXP 64
#define NCOL  128              // route cols 0..63 | noise cols 64..127
#define BM    32               // tokens per block (grid 512 -> 2 blocks/CU)
#define BK    64               // K per main-loop iteration (2 MFMA substeps of 32)
#define NITER (D_DIM / BK)     // 32

// LDS: A limbs, frag-linear. Per row: 128B payload (64 k bf16) + 16B skew.
// Row stride 144B = 36 words; 36 % 32 = 4 -> bank quad = 4*((row+chunk)&7),
// 8 lanes/quad for full-wave b128 reads (balanced, no XOR).
#define ROW_STRIDE 144
#define PLANE (BM * ROW_STRIDE)        // 4608 B per limb plane
#define BUFSZ (3 * PLANE)              // 13824 B per K-tile buffer (3 limbs)
#define SMEM_BYTES (2 * BUFSZ)         // 27648 B (epilogue Llds aliases: 32*132*4=16.9KB)

typedef float         f32x4  __attribute__((ext_vector_type(4)));
typedef short         bf16x8 __attribute__((ext_vector_type(8)));
typedef unsigned int  uint;

#define MFMA_B16(a, b, c) __builtin_amdgcn_mfma_f32_16x16x32_bf16((a), (b), (c), 0, 0, 0)

// f32 -> bf16 round-to-nearest-even (used for limb 2 and for prep_w)
__device__ __forceinline__ unsigned short bfrne(float f) {
    unsigned int u = __float_as_uint(f);
    return (unsigned short)((u + 0x7fffu + ((u >> 16) & 1u)) >> 16);
}
__device__ __forceinline__ float bfhi(unsigned short h) {
    return __uint_as_float((unsigned int)h << 16);
}

// jax.lax.top_k order: larger value first; ties -> lower index first
__device__ __forceinline__ bool beats(float va, int ia, float vb, int ib) {
    return (va > vb) || (va == vb && ia < ib);
}

// ---------------- prep: split W_route|W_noise into 3 bf16 limbs, frag-linear ----------
// Wg layout (16B units): [kblk 0..63][limb 0..2][cf 0..7][lane 0..63]
//   cf 0..3 -> route cols cf*16+(lane&15); cf 4..7 -> noise cols (cf-4)*16+(lane&15)
//   lane holds k = kblk*32 + (lane>>4)*8 + j  (exactly the mfma_16x16x32 B-frag order)
__global__ __launch_bounds__(256) void prep_w(
    const float* __restrict__ Wr, const float* __restrict__ Wn,
    unsigned short* __restrict__ Wg)
{
    const int g    = blockIdx.x * 256 + threadIdx.x;   // 0..32767
    const int lane = g & 63;
    const int cf   = (g >> 6) & 7;
    const int kblk = g >> 9;                           // 0..63
    const int colL = (cf & 3) * 16 + (lane & 15);
    const float* __restrict__ W = (cf < 4) ? Wr : Wn;
    const int kbase = kblk * 32 + (lane >> 4) * 8;

    bf16x8 o0, o1, o2;
    #pragma unroll
    for (int j = 0; j < 8; ++j) {
        const float w = W[(size_t)(kbase + j) * E_EXP + colL];
        const unsigned short h0 = bfrne(w);
        const float r  = w - bfhi(h0);              // exact
        const unsigned short h1 = bfrne(r);
        const float r2 = r - bfhi(h1);              // exact
        const unsigned short h2 = bfrne(r2);
        o0[j] = (short)h0; o1[j] = (short)h1; o2[j] = (short)h2;
    }
    const size_t s0 = (((size_t)kblk * 3 + 0) * 8 + cf) * 64 + lane;
    const size_t s1 = (((size_t)kblk * 3 + 1) * 8 + cf) * 64 + lane;
    const size_t s2 = (((size_t)kblk * 3 + 2) * 8 + cf) * 64 + lane;
    *(bf16x8*)(Wg + s0 * 8) = o0;
    *(bf16x8*)(Wg + s1 * 8) = o1;
    *(bf16x8*)(Wg + s2 * 8) = o2;
}

// ---------------- fused: 3-limb bf16 MFMA GEMM + softplus + top-2 + softmax ----------
// Wave wid owns cols [wid*16, wid*16+16) of the 128 (route|noise) columns and all
// 32 tokens -> B frags per K-iter: 2 kblk x 3 limbs x 1 cf = 6 (24 VGPR/buffer).
__device__ __forceinline__ void load_b(const unsigned short* __restrict__ Wg,
                                       int it, int wc, int lane,
                                       bf16x8 (&Bv)[2][3])
{
    #pragma unroll
    for (int s = 0; s < 2; ++s) {
        const int kblk = it * 2 + s;
        #pragma unroll
        for (int p = 0; p < 3; ++p) {
            const size_t idx = (((size_t)kblk * 3 + p) * 8 + wc) * 64 + lane;
            Bv[s][p] = *(const bf16x8*)(Wg + idx * 8);
        }
    }
}

// A tile 32 tok x 64 k: one float4 per thread (512 threads * 16B = 8KB)
__device__ __forceinline__ void load_a(const float* __restrict__ A, int tokBase,
                                       int it, int tid, float4& x)
{
    const int row = tid >> 4;          // 0..31
    const int kc  = tid & 15;          // 4-float chunk within the 64-wide K tile
    x = *(const float4*)(A + (size_t)(tokBase + row) * D_DIM + it * BK + kc * 4);
}

// split this thread's 4 A-floats into 3 bf16 limb half-chunks; store b64 to LDS.
// limbs 0,1 by truncation (hi bits already positioned -> cheap pack);
// limb 2 by RNE. Residuals exact; total split residual <= 2^-25 relative.
__device__ __forceinline__ void cvt_store(char* smem, int buf, int tid, const float4& x)
{
    const float v[4] = {x.x, x.y, x.z, x.w};
    uint t0[4], t1[4]; unsigned short h2[4];
    #pragma unroll
    for (int j = 0; j < 4; ++j) {
        const uint u = __float_as_uint(v[j]);
        t0[j] = u & 0xffff0000u;
        const float r = v[j] - __uint_as_float(t0[j]);      // exact
        const uint ru = __float_as_uint(r);
        t1[j] = ru & 0xffff0000u;
        const float r2 = r - __uint_as_float(t1[j]);        // exact
        h2[j] = bfrne(r2);
    }
    uint2 w0, w1, w2;
    w0.x = (t0[0] >> 16) | t0[1];  w0.y = (t0[2] >> 16) | t0[3];
    w1.x = (t1[0] >> 16) | t1[1];  w1.y = (t1[2] >> 16) | t1[3];
    w2.x = (uint)h2[0] | ((uint)h2[1] << 16);
    w2.y = (uint)h2[2] | ((uint)h2[3] << 16);

    const int row = tid >> 4;
    const int kc  = tid & 15;          // 8B chunk within the 128B row
    char* base = smem + buf * BUFSZ + row * ROW_STRIDE + kc * 8;
    *(uint2*)(base)             = w0;
    *(uint2*)(base + PLANE)     = w1;
    *(uint2*)(base + 2 * PLANE) = w2;
}

__device__ __forceinline__ void compute_iter(const char* Ab, int lane,
                                             const bf16x8 (&Bc)[2][3],
                                             f32x4 (&acch)[2], f32x4 (&accl)[2])
{
    #pragma unroll
    for (int s = 0; s < 2; ++s) {
        #pragma unroll
        for (int rf = 0; rf < 2; ++rf) {
            const int row = rf * 16 + (lane & 15);
            const int off = row * ROW_STRIDE + (s * 4 + (lane >> 4)) * 16;
            const bf16x8 a0 = *(const bf16x8*)(Ab + off);
            const bf16x8 a1 = *(const bf16x8*)(Ab + PLANE + off);
            const bf16x8 a2 = *(const bf16x8*)(Ab + 2 * PLANE + off);
            // hi limb product -> short dep chain in acch; 5 low products -> accl
            acch[rf] = MFMA_B16(a0, Bc[s][0], acch[rf]);
            accl[rf] = MFMA_B16(a0, Bc[s][1], accl[rf]);
            accl[rf] = MFMA_B16(a1, Bc[s][0], accl[rf]);
            accl[rf] = MFMA_B16(a1, Bc[s][1], accl[rf]);
            accl[rf] = MFMA_B16(a0, Bc[s][2], accl[rf]);
            accl[rf] = MFMA_B16(a2, Bc[s][0], accl[rf]);
        }
    }
}

#define LL_LD 132   // Llds row stride (floats): 16B-aligned rows, 132%32=4 skew

__global__ __launch_bounds__(512) void fused_router(
    const float* __restrict__ A,
    const unsigned short* __restrict__ Wg,
    const float* __restrict__ br, const float* __restrict__ bn,
    const float* __restrict__ noise,
    float* __restrict__ probs, float* __restrict__ idxo)
{
    __shared__ __align__(16) char smem[SMEM_BYTES];   // A limbs (2 buf); epilogue aliases

    const int tid  = threadIdx.x;
    const int lane = tid & 63;
    const int wc   = tid >> 6;       // 0..7: this wave's 16-col slice of 128
    const int tokBase = blockIdx.x * BM;

    f32x4 acch[2], accl[2];
    const f32x4 zero4 = {0.f, 0.f, 0.f, 0.f};
    acch[0] = zero4; acch[1] = zero4; accl[0] = zero4; accl[1] = zero4;

    bf16x8 B0[2][3], B1[2][3];
    float4 xE, xO;

    // prologue: limbs(0) -> buf0; A(1) in flight; B(0) in regs
    load_a(A, tokBase, 0, tid, xE);
    load_b(Wg, 0, wc, lane, B0);
    load_a(A, tokBase, 1, tid, xO);
    cvt_store(smem, 0, tid, xE);
    __syncthreads();

    #pragma unroll 1
    for (int it2 = 0; it2 < NITER / 2; ++it2) {
        const int ita = it2 * 2;
        const int itb = ita + 1;              // < NITER (NITER even)

        load_b(Wg, itb, wc, lane, B1);        // B for the odd sub-iter
        cvt_store(smem, 1, tid, xO);          // limbs(itb) -> buf1
        if (ita + 2 < NITER) load_a(A, tokBase, ita + 2, tid, xE);   // deep prefetch
        compute_iter(smem, lane, B0, acch, accl);                    // consume buf0
        __syncthreads();                      // buf1 ready; buf0 reads done

        if (itb + 1 < NITER) load_b(Wg, itb + 1, wc, lane, B0);
        if (ita + 2 < NITER) cvt_store(smem, 0, tid, xE);            // limbs(ita+2) -> buf0
        if (itb + 2 < NITER) load_a(A, tokBase, itb + 2, tid, xO);
        compute_iter(smem + BUFSZ, lane, B1, acch, accl);            // consume buf1
        __syncthreads();                      // buf0 ready; buf1 reads done
    }

    // ---- accumulators -> LDS logits (C layout: col=lane&15, row=(lane>>4)*4+reg) ----
    float (*Llds)[LL_LD] = (float (*)[LL_LD])smem;   // 32 x 132 f32, aliases A bufs
    {
        const int col = wc * 16 + (lane & 15);
        #pragma unroll
        for (int rf = 0; rf < 2; ++rf) {
            const int rowb = rf * 16 + (lane >> 4) * 4;
            #pragma unroll
            for (int r = 0; r < 4; ++r)
                Llds[rowb + r][col] = acch[rf][r] + accl[rf][r];
        }
    }
    __syncthreads();

    // ---- fused epilogue: 16 lanes per token, 4 experts each (f32) ----
    const int token = tid >> 4;          // 0..31
    const int s16   = tid & 15;
    const int tokG  = tokBase + token;

    float v0 = -INFINITY, v1 = -INFINITY;
    int i0 = 0, i1 = 0;
    {
        const float4 n4 = *(const float4*)(noise + (size_t)tokG * E_EXP + s16 * 4);
        const float4 b4 = *(const float4*)(br + s16 * 4);
        const float4 c4 = *(const float4*)(bn + s16 * 4);
        const float4 l4 = *(const float4*)(&Llds[token][s16 * 4]);
        const float4 m4 = *(const float4*)(&Llds[token][64 + s16 * 4]);
        const float nv[4] = {n4.x, n4.y, n4.z, n4.w};
        const float bv[4] = {b4.x, b4.y, b4.z, b4.w};
        const float cv[4] = {c4.x, c4.y, c4.z, c4.w};
        const float lv[4] = {l4.x, l4.y, l4.z, l4.w};
        const float mv[4] = {m4.x, m4.y, m4.z, m4.w};
        #pragma unroll
        for (int j = 0; j < 4; ++j) {
            const int e = s16 * 4 + j;
            const float lg = lv[j] + bv[j];
            const float nl = mv[j] + cv[j];
            const float sp = fmaxf(nl, 0.0f) + log1pf(expf(-fabsf(nl)));   // softplus
            const float v  = fmaf(nv[j], sp, lg);
            if (beats(v, e, v0, i0))      { v1 = v0; i1 = i0; v0 = v; i0 = e; }
            else if (beats(v, e, v1, i1)) { v1 = v;  i1 = e; }
        }
    }
    // merge across the token's 16 lanes (aligned group, masks 1,2,4,8)
    #pragma unroll
    for (int m = 1; m < 16; m <<= 1) {
        const float w0 = __shfl_xor(v0, m), w1 = __shfl_xor(v1, m);
        const int   j0 = __shfl_xor(i0, m), j1 = __shfl_xor(i1, m);
        if (beats(v0, i0, w0, j0)) {
            if (!beats(v1, i1, w0, j0)) { v1 = w0; i1 = j0; }
        } else {
            if (beats(v0, i0, w1, j1)) { v1 = v0; i1 = i0; }
            else                       { v1 = w1; i1 = j1; }
            v0 = w0; i0 = j0;
        }
    }
    const float e1  = expf(v1 - v0);     // <= 1
    const float den = 1.0f + e1;
    const float p0 = 1.0f / den;
    const float p1 = e1 / den;

    // every lane writes its own 4 cols -> no cross-thread write ordering needed
    float out[4];
    #pragma unroll
    for (int j = 0; j < 4; ++j) {
        const int e = s16 * 4 + j;
        out[j] = (e == i0) ? p0 : ((e == i1) ? p1 : 0.0f);
    }
    *(float4*)(probs + (size_t)tokG * E_EXP + s16 * 4) =
        make_float4(out[0], out[1], out[2], out[3]);
    if (s16 == 0)
        *(float2*)(idxo + (size_t)tokG * 2) = make_float2((float)i0, (float)i1);
}

extern "C" void kernel_launch(void* const* d_in, const int* in_sizes, int n_in,
                              void* d_out, int out_size, void* d_ws, size_t ws_size,
                              hipStream_t stream) {
    (void)in_sizes; (void)n_in; (void)out_size; (void)ws_size;
    const float* A  = (const float*)d_in[0];   // mh_output [4,4096,2048]
    const float* Wr = (const float*)d_in[1];   // W_route   [2048,64]
    const float* br = (const float*)d_in[2];   // b_route   [64]
    const float* Wn = (const float*)d_in[3];   // W_noise   [2048,64]
    const float* bn = (const float*)d_in[4];   // b_noise   [64]
    const float* nz = (const float*)d_in[5];   // noise     [4,4096,64]

    float* probs = (float*)d_out;                    // [4,4096,64] f32
    float* idxo  = probs + (size_t)M_TOK * E_EXP;    // [4,4096,2] as float

    unsigned short* Wg = (unsigned short*)d_ws;      // 1.5 MB split-W, frag-linear

    prep_w<<<128, 256, 0, stream>>>(Wr, Wn, Wg);
    fused_router<<<M_TOK / BM, 512, 0, stream>>>(A, Wg, br, bn, nz, probs, idxo);
}

// Round 6
// 230.305 us; speedup vs baseline: 1.8497x; 1.0461x over previous
//
#include <hip/hip_runtime.h>
#include <math.h>

// Problem: B=4, S=4096, D=2048, E=64, TOP_K=2
#define M_TOK 16384
#define D_DIM 2048
#define E_EXP 64
#define BM    32               // tokens per block (grid 512 -> 2 blocks/CU)
#define NT_H  16               // K64 tiles per K-half (2 halves -> 32 tiles = 2048 K)
#define FRAG_B 1040            // A-frag stride: 1024B payload + 16B pad (260 words %32 = 4)
#define TILE_B (12 * FRAG_B)   // 12 frags (4 ksteps x 3 limbs) per K64 tile = 12480 B
#define SMEM_BYTES (4 * TILE_B) // 49920 B: {kh0,kh1} x {parity0,parity1}
#define LL_LD 132              // epilogue logits row stride (floats)

typedef float         f32x16 __attribute__((ext_vector_type(16)));
typedef short         bf16x8 __attribute__((ext_vector_type(8)));
typedef unsigned int  uint;

#define MFMA32(a, b, c) __builtin_amdgcn_mfma_f32_32x32x16_bf16((a), (b), (c), 0, 0, 0)

// f32 -> bf16 round-to-nearest-even
__device__ __forceinline__ unsigned short bfrne(float f) {
    unsigned int u = __float_as_uint(f);
    return (unsigned short)((u + 0x7fffu + ((u >> 16) & 1u)) >> 16);
}
__device__ __forceinline__ float bfhi(unsigned short h) {
    return __uint_as_float((unsigned int)h << 16);
}

// jax.lax.top_k order: larger value first; ties -> lower index first
__device__ __forceinline__ bool beats(float va, int ia, float vb, int ib) {
    return (va > vb) || (va == vb && ia < ib);
}

// ---------------- prep: split W into 3 bf16 limbs as 32x32x16 B-frags ----------------
// Wg (16B units): [kstep 0..127][limb 0..2][ch 0..3][lane 0..63]
//   frag lane l: col = ch*32 + (l&31)  (cols 0..63 route, 64..127 noise)
//                k   = kstep*16 + (l>>5)*8 + j   (exact mfma_32x32x16 B-frag order)
__global__ __launch_bounds__(256) void prep_w(
    const float* __restrict__ Wr, const float* __restrict__ Wn,
    unsigned short* __restrict__ Wg)
{
    const int g     = blockIdx.x * 256 + threadIdx.x;  // 0..32767
    const int lane  = g & 63;
    const int ch    = (g >> 6) & 3;
    const int kstep = g >> 8;                          // 0..127
    const int col   = ch * 32 + (lane & 31);
    const float* __restrict__ W = (col < 64) ? Wr : Wn;
    const int colL  = col & 63;
    const int kbase = kstep * 16 + (lane >> 5) * 8;

    bf16x8 o0, o1, o2;
    #pragma unroll
    for (int j = 0; j < 8; ++j) {
        const float w = W[(size_t)(kbase + j) * E_EXP + colL];
        const unsigned short h0 = bfrne(w);
        const float r  = w - bfhi(h0);              // exact
        const unsigned short h1 = bfrne(r);
        const float r2 = r - bfhi(h1);              // exact
        const unsigned short h2 = bfrne(r2);
        o0[j] = (short)h0; o1[j] = (short)h1; o2[j] = (short)h2;
    }
    #pragma unroll
    for (int p = 0; p < 3; ++p) {
        const size_t idx = (((size_t)kstep * 3 + p) * 4 + ch) * 64 + lane;
        const bf16x8 o = (p == 0) ? o0 : (p == 1) ? o1 : o2;
        *(bf16x8*)(Wg + idx * 8) = o;
    }
}

// ---------------- fused: 3-limb bf16 32x32x16 MFMA + softplus + top-2 + softmax -------
// load 6 B-frags (2 ksteps) for tile t starting at kstep-pair s0
__device__ __forceinline__ void load_b_half(const unsigned short* __restrict__ Wg,
                                            int t, int s0, int wc, int lane,
                                            bf16x8 (&Bv)[2][3])
{
    #pragma unroll
    for (int s = 0; s < 2; ++s) {
        const int kstep = t * 4 + s0 + s;
        #pragma unroll
        for (int p = 0; p < 3; ++p) {
            const size_t idx = (((size_t)kstep * 3 + p) * 4 + wc);
            Bv[s][p] = *(const bf16x8*)(Wg + (idx << 9) + lane * 8);
        }
    }
}

// A tile 32 tok x 64 k: one float4 per thread (512 threads * 16B = 8KB f32)
__device__ __forceinline__ void load_a(const float* __restrict__ A, int tokBase,
                                       int t, int tid, float4& x)
{
    const int row = tid >> 4;          // 0..31
    const int kc  = tid & 15;
    x = *(const float4*)(A + (size_t)(tokBase + row) * D_DIM + t * 64 + kc * 4);
}

// split 4 floats -> 3 limb 8B pieces, scatter into frag-linear tile buffer.
// limbs 0,1 truncation (exact residuals), limb 2 RNE; total residual <= 2^-25 rel.
__device__ __forceinline__ void cvt_store(char* tbase, int tid, const float4& x)
{
    const float v[4] = {x.x, x.y, x.z, x.w};
    uint t0[4], t1[4]; unsigned short h2[4];
    #pragma unroll
    for (int j = 0; j < 4; ++j) {
        const uint u = __float_as_uint(v[j]);
        t0[j] = u & 0xffff0000u;
        const float r = v[j] - __uint_as_float(t0[j]);      // exact
        const uint ru = __float_as_uint(r);
        t1[j] = ru & 0xffff0000u;
        const float r2 = r - __uint_as_float(t1[j]);        // exact
        h2[j] = bfrne(r2);
    }
    uint2 w0, w1, w2;
    w0.x = (t0[0] >> 16) | t0[1];  w0.y = (t0[2] >> 16) | t0[3];
    w1.x = (t1[0] >> 16) | t1[1];  w1.y = (t1[2] >> 16) | t1[3];
    w2.x = (uint)h2[0] | ((uint)h2[1] << 16);
    w2.y = (uint)h2[2] | ((uint)h2[3] << 16);

    const int row   = tid >> 4;
    const int kc    = tid & 15;         // k = kc*4 within the 64-wide tile
    const int kstep = kc >> 2;          // 0..3
    const int hoct  = (kc >> 1) & 1;    // k-octet within kstep
    const int half  = kc & 1;           // lower/upper 8B of the lane's 16B
    const int l     = hoct * 32 + row;  // frag lane index
    char* p = tbase + kstep * (3 * FRAG_B) + l * 16 + half * 8;
    *(uint2*)(p)              = w0;
    *(uint2*)(p + FRAG_B)     = w1;
    *(uint2*)(p + 2 * FRAG_B) = w2;
}

// 2 ksteps: 6 linear ds_read_b128 + 12 MFMA(32x32x16)
__device__ __forceinline__ void compute_half(const char* tbase, int s0, int lane,
                                             const bf16x8 (&Bv)[2][3],
                                             f32x16& acch, f32x16& accl)
{
    const char* ap = tbase + lane * 16;
    #pragma unroll
    for (int s = 0; s < 2; ++s) {
        const int f = (s0 + s) * 3;
        const bf16x8 a0 = *(const bf16x8*)(ap + (f + 0) * FRAG_B);
        const bf16x8 a1 = *(const bf16x8*)(ap + (f + 1) * FRAG_B);
        const bf16x8 a2 = *(const bf16x8*)(ap + (f + 2) * FRAG_B);
        // hi limb product -> short dep chain in acch; 5 low products -> accl
        acch = MFMA32(a0, Bv[s][0], acch);
        accl = MFMA32(a0, Bv[s][1], accl);
        accl = MFMA32(a1, Bv[s][0], accl);
        accl = MFMA32(a1, Bv[s][1], accl);
        accl = MFMA32(a0, Bv[s][2], accl);
        accl = MFMA32(a2, Bv[s][0], accl);
    }
}

__global__ __launch_bounds__(512) void fused_router(
    const float* __restrict__ A,
    const unsigned short* __restrict__ Wg,
    const float* __restrict__ br, const float* __restrict__ bn,
    const float* __restrict__ noise,
    float* __restrict__ probs, float* __restrict__ idxo)
{
    __shared__ __align__(16) char smem[SMEM_BYTES];   // 4 tile buffers; epilogue aliases

    const int tid  = threadIdx.x;
    const int lane = tid & 63;
    const int wid  = tid >> 6;       // 0..7
    const int wc   = wid & 3;        // 32-col slice of 128 (route|noise)
    const int kh   = wid >> 2;       // K half: tiles [0,16) or [16,32)
    const int tokBase = blockIdx.x * BM;

    f32x16 acch, accl;
    #pragma unroll
    for (int r = 0; r < 16; ++r) { acch[r] = 0.f; accl[r] = 0.f; }

    char* st0a = smem;                    // kh0 parity0
    char* st0b = smem + TILE_B;           // kh0 parity1
    char* st1a = smem + 2 * TILE_B;       // kh1 parity0
    char* st1b = smem + 3 * TILE_B;       // kh1 parity1
    const char* myBuf0 = smem + (kh * 2 + 0) * TILE_B;
    const char* myBuf1 = smem + (kh * 2 + 1) * TILE_B;

    float4 x0, x1, y0, y1;
    bf16x8 Bv[2][3];

    // prologue: tiles (0,16) -> parity0; tiles (1,17) in regs
    load_a(A, tokBase, 0,        tid, x0);
    load_a(A, tokBase, NT_H,     tid, x1);
    cvt_store(st0a, tid, x0);
    cvt_store(st1a, tid, x1);
    load_a(A, tokBase, 1,        tid, x0);
    load_a(A, tokBase, NT_H + 1, tid, x1);
    __syncthreads();

    #pragma unroll 1
    for (int it2 = 0; it2 < NT_H / 2; ++it2) {
        const int itA = 2 * it2;
        const int tA  = kh * NT_H + itA;

        // ---- body A: compute parity0 (tile tA) ----
        load_b_half(Wg, tA, 0, wc, lane, Bv);
        cvt_store(st0b, tid, x0);                 // tiles itA+1 / 16+itA+1 -> parity1
        cvt_store(st1b, tid, x1);
        if (itA + 2 < NT_H) {
            load_a(A, tokBase, itA + 2,        tid, y0);
            load_a(A, tokBase, NT_H + itA + 2, tid, y1);
        }
        compute_half(myBuf0, 0, lane, Bv, acch, accl);
        load_b_half(Wg, tA, 2, wc, lane, Bv);
        compute_half(myBuf0, 2, lane, Bv, acch, accl);
        __syncthreads();

        // ---- body B: compute parity1 (tile tA+1) ----
        load_b_half(Wg, tA + 1, 0, wc, lane, Bv);
        if (itA + 2 < NT_H) { cvt_store(st0a, tid, y0); cvt_store(st1a, tid, y1); }
        if (itA + 3 < NT_H) {
            load_a(A, tokBase, itA + 3,        tid, x0);
            load_a(A, tokBase, NT_H + itA + 3, tid, x1);
        }
        compute_half(myBuf1, 0, lane, Bv, acch, accl);
        load_b_half(Wg, tA + 1, 2, wc, lane, Bv);
        compute_half(myBuf1, 2, lane, Bv, acch, accl);
        __syncthreads();
    }

    // ---- accumulators -> LDS logits; K-halves into separate slabs, summed in epilogue.
    // 32x32 C layout: col = lane&31, row = (r&3) + 8*(r>>2) + 4*(lane>>5)
    float (*Ll)[BM][LL_LD] = (float (*)[BM][LL_LD])smem;   // [2][32][132], aliases bufs
    {
        const int col   = wc * 32 + (lane & 31);
        const int rbase = 4 * (lane >> 5);
        #pragma unroll
        for (int r = 0; r < 16; ++r) {
            const int row = (r & 3) + 8 * (r >> 2) + rbase;
            Ll[kh][row][col] = acch[r] + accl[r];
        }
    }
    __syncthreads();

    // ---- fused epilogue: 16 lanes per token, 4 experts each (f32) ----
    const int token = tid >> 4;          // 0..31
    const int s16   = tid & 15;
    const int tokG  = tokBase + token;

    float v0 = -INFINITY, v1 = -INFINITY;
    int i0 = 0, i1 = 0;
    {
        const float4 n4 = *(const float4*)(noise + (size_t)tokG * E_EXP + s16 * 4);
        const float4 b4 = *(const float4*)(br + s16 * 4);
        const float4 c4 = *(const float4*)(bn + s16 * 4);
        const float4 la = *(const float4*)(&Ll[0][token][s16 * 4]);
        const float4 lb = *(const float4*)(&Ll[1][token][s16 * 4]);
        const float4 ma = *(const float4*)(&Ll[0][token][64 + s16 * 4]);
        const float4 mb = *(const float4*)(&Ll[1][token][64 + s16 * 4]);
        const float nv[4] = {n4.x, n4.y, n4.z, n4.w};
        const float bv[4] = {b4.x, b4.y, b4.z, b4.w};
        const float cv[4] = {c4.x, c4.y, c4.z, c4.w};
        const float lv[4] = {la.x + lb.x, la.y + lb.y, la.z + lb.z, la.w + lb.w};
        const float mv[4] = {ma.x + mb.x, ma.y + mb.y, ma.z + mb.z, ma.w + mb.w};
        #pragma unroll
        for (int j = 0; j < 4; ++j) {
            const int e = s16 * 4 + j;
            const float lg = lv[j] + bv[j];
            const float nl = mv[j] + cv[j];
            const float sp = fmaxf(nl, 0.0f) + log1pf(expf(-fabsf(nl)));   // softplus
            const float v  = fmaf(nv[j], sp, lg);
            if (beats(v, e, v0, i0))      { v1 = v0; i1 = i0; v0 = v; i0 = e; }
            else if (beats(v, e, v1, i1)) { v1 = v;  i1 = e; }
        }
    }
    // merge across the token's 16 lanes (aligned group, masks 1,2,4,8)
    #pragma unroll
    for (int m = 1; m < 16; m <<= 1) {
        const float w0 = __shfl_xor(v0, m), w1 = __shfl_xor(v1, m);
        const int   j0 = __shfl_xor(i0, m), j1 = __shfl_xor(i1, m);
        if (beats(v0, i0, w0, j0)) {
            if (!beats(v1, i1, w0, j0)) { v1 = w0; i1 = j0; }
        } else {
            if (beats(v0, i0, w1, j1)) { v1 = v0; i1 = i0; }
            else                       { v1 = w1; i1 = j1; }
            v0 = w0; i0 = j0;
        }
    }
    const float e1  = expf(v1 - v0);     // <= 1
    const float den = 1.0f + e1;
    const float p0 = 1.0f / den;
    const float p1 = e1 / den;

    float out[4];
    #pragma unroll
    for (int j = 0; j < 4; ++j) {
        const int e = s16 * 4 + j;
        out[j] = (e == i0) ? p0 : ((e == i1) ? p1 : 0.0f);
    }
    *(float4*)(probs + (size_t)tokG * E_EXP + s16 * 4) =
        make_float4(out[0], out[1], out[2], out[3]);
    if (s16 == 0)
        *(float2*)(idxo + (size_t)tokG * 2) = make_float2((float)i0, (float)i1);
}

extern "C" void kernel_launch(void* const* d_in, const int* in_sizes, int n_in,
                              void* d_out, int out_size, void* d_ws, size_t ws_size,
                              hipStream_t stream) {
    (void)in_sizes; (void)n_in; (void)out_size; (void)ws_size;
    const float* A  = (const float*)d_in[0];   // mh_output [4,4096,2048]
    const float* Wr = (const float*)d_in[1];   // W_route   [2048,64]
    const float* br = (const float*)d_in[2];   // b_route   [64]
    const float* Wn = (const float*)d_in[3];   // W_noise   [2048,64]
    const float* bn = (const float*)d_in[4];   // b_noise   [64]
    const float* nz = (const float*)d_in[5];   // noise     [4,4096,64]

    float* probs = (float*)d_out;                    // [4,4096,64] f32
    float* idxo  = probs + (size_t)M_TOK * E_EXP;    // [4,4096,2] as float

    unsigned short* Wg = (unsigned short*)d_ws;      // 1.57 MB split-W, frag-linear

    prep_w<<<128, 256, 0, stream>>>(Wr, Wn, Wg);
    fused_router<<<M_TOK / BM, 512, 0, stream>>>(A, Wg, br, bn, nz, probs, idxo);
}